// Round 1
// baseline (146.636 us; speedup 1.0000x reference)
//
#include <hip/hip_runtime.h>
#include <stdint.h>

// Problem dims
#define TDIM 4096
#define HDIM 2048   // N and K of the GEMM

// GEMM tile
#define BM 128
#define BN 128
#define BK 64
#define NKT (HDIM / BK)   // 32
// LDS: per buffer = A region (144 rows = 18 groups of 8 rows, 1KB/group)
//      + B region (128 rows = 16 groups), 128B per row (BK=64 bf16)
#define AREG  18432
#define PERBUF 34816
#define SSTR   132        // S-tile row stride in elements (breaks bank conflicts)

typedef short short8 __attribute__((ext_vector_type(8)));
typedef float f32x4 __attribute__((ext_vector_type(4)));

__device__ __forceinline__ uint16_t f2bf(float f) {
  uint32_t u = __builtin_bit_cast(uint32_t, f);
  u += 0x7fffu + ((u >> 16) & 1u);          // round-to-nearest-even
  return (uint16_t)(u >> 16);
}
__device__ __forceinline__ float bf2f(uint32_t h) {   // low 16 bits used
  uint32_t u = h << 16;
  return __builtin_bit_cast(float, u);
}

__device__ __forceinline__ void async_copy16(const void* gsrc, void* ldst) {
  __builtin_amdgcn_global_load_lds(
      (const __attribute__((address_space(1))) uint32_t*)gsrc,
      (__attribute__((address_space(3))) uint32_t*)ldst,
      16, 0, 0);
}

// ------------- prep: cvt x (fp32->bf16) + transpose/cvt B -> Bt -------------
__global__ void prep(const float* __restrict__ x, const float* __restrict__ B,
                     uint16_t* __restrict__ xb, uint16_t* __restrict__ Bt) {
  __shared__ uint16_t tile[64][68];
  const int t = threadIdx.x;
  if (blockIdx.x < 4096) {
    size_t i = ((size_t)blockIdx.x * 256 + t) * 8;
    float4 v0 = *(const float4*)(x + i);
    float4 v1 = *(const float4*)(x + i + 4);
    union { uint16_t h[8]; uint4 v; } o;
    o.h[0] = f2bf(v0.x); o.h[1] = f2bf(v0.y); o.h[2] = f2bf(v0.z); o.h[3] = f2bf(v0.w);
    o.h[4] = f2bf(v1.x); o.h[5] = f2bf(v1.y); o.h[6] = f2bf(v1.z); o.h[7] = f2bf(v1.w);
    *(uint4*)(xb + i) = o.v;
  } else {
    const int bid = blockIdx.x - 4096;
    const int n0 = (bid & 31) * 64;
    const int k0 = (bid >> 5) * 64;
    {
      const int r  = t >> 4;
      const int c4 = (t & 15) * 4;
#pragma unroll
      for (int i = 0; i < 4; ++i) {
        int rr = r + i * 16;
        float4 v = *(const float4*)&B[(size_t)(k0 + rr) * HDIM + n0 + c4];
        union { uint16_t h[4]; uint2 u; } o;
        o.h[0] = f2bf(v.x); o.h[1] = f2bf(v.y); o.h[2] = f2bf(v.z); o.h[3] = f2bf(v.w);
        *(uint2*)&tile[rr][c4] = o.u;
      }
    }
    __syncthreads();
    {
      const int nr = t >> 2;
      const int kc = (t & 3) * 4;
#pragma unroll
      for (int i = 0; i < 4; ++i) {
        int kk = kc + i * 16;
        union { uint16_t h[4]; uint2 u; } o;
        o.h[0] = tile[kk][nr];     o.h[1] = tile[kk + 1][nr];
        o.h[2] = tile[kk + 2][nr]; o.h[3] = tile[kk + 3][nr];
        *(uint2*)&Bt[(size_t)(n0 + nr) * HDIM + k0 + kk] = o.u;
      }
    }
  }
}

// --------- fused GEMM + causal exp-decay recurrence (scan) ---------
// S[t][n] = sum_k A[t][k]*Bt[n][k]; out[t][h] = S[t][h] + a[h]*out[t-1][h].
// 128 threads = 2 waves, each a 128x64 tile (8x4 acc). LDS-read traffic per
// FLOP ~ (Mw+Nw)/(Mw*Nw): 128x64 waves cut per-CU LDS reads 136->104 KB/kt
// vs 64x64 (B rows now read by exactly one wave) and double per-wave ILP.
// 2 blocks/CU (LDS-limited) keeps the cross-block barrier stagger.
// BK=64: 128B rows + XOR-8 chunk swizzle = conflict-free.
// 16 warmup rows (both waves, own columns); in-LDS S-tile scan epilogue
// (|a| <= 2^-5 -> a^16 below fp32 noise, blocks independent).
__global__ __launch_bounds__(128, 1) void gemm_scan(
    const uint16_t* __restrict__ A, const uint16_t* __restrict__ Bt,
    const float* __restrict__ a, float* __restrict__ out) {
  __shared__ __align__(16) char lds[2 * PERBUF];   // 69632

  const int tid  = threadIdx.x;
  const int lane = tid & 63;
  const int wave = tid >> 6;            // 0..1
  const int wn = wave * 64;             // wave col offset {0,64}
  const int m0 = blockIdx.y * BM;
  const int n0 = blockIdx.x * BN;

  f32x4 acc[8][4] = {};
  f32x4 accw[4] = {};                   // warmup rows (each wave: own cols)

  // staging: one instr = 8 rows x 128B (1KB); lane l: row lr=l>>3, slot l&7,
  // fetches global chunk (l&7)^lr -> LDS slot c of row r holds chunk c^(r&7)
  const int lr = lane >> 3;             // 0..7
  const int gc = (lane & 7) ^ lr;       // swizzled 16B chunk to fetch

  const int fr = lane & 15;
  const int fq = lane >> 4;             // 0..3

  // A: 18 groups of 8 rows (t in [m0-16, m0+128)); B: 16 groups.
  // wave 0: A groups 0..16 (17 loads); wave 1: A group 17 + B groups 0..15
  // (17 loads). Symmetric 17/wave -> uniform vmcnt(17).
  auto issue_tile = [&](int kt2) {
    size_t koff = (size_t)kt2 * (BK * 2);
    char* dst = lds + (kt2 & 1) * PERBUF;
    if (wave == 0) {
#pragma unroll
      for (int i = 0; i < 17; ++i) {
        int row = m0 - 16 + i * 8 + lr;
        if (row < 0) row = 0;           // m0==0: garbage rows, never used
        async_copy16((const char*)A + ((size_t)row * HDIM + gc * 8) * 2 + koff,
                     dst + i * 1024);
      }
    } else {
      {
        int row = m0 - 16 + 17 * 8 + lr;   // rows m0+120..m0+127: always valid
        async_copy16((const char*)A + ((size_t)row * HDIM + gc * 8) * 2 + koff,
                     dst + 17 * 1024);
      }
#pragma unroll
      for (int i = 0; i < 16; ++i) {
        int row = n0 + i * 8 + lr;
        async_copy16((const char*)Bt + ((size_t)row * HDIM + gc * 8) * 2 + koff,
                     dst + AREG + i * 1024);
      }
    }
  };

  issue_tile(0);
  for (int kt = 0; kt < NKT; ++kt) {
    if (kt + 1 < NKT) {
      issue_tile(kt + 1);
      // wait only this tile's 17 loads; next tile's 17 stay in flight
      asm volatile("s_waitcnt vmcnt(17)" ::: "memory");
    } else {
      asm volatile("s_waitcnt vmcnt(0)" ::: "memory");
    }
    asm volatile("s_barrier" ::: "memory");

    const char* base = lds + (kt & 1) * PERBUF;
#pragma unroll
    for (int s = 0; s < 2; ++s) {       // two K=32 halves of the 128B row
      short8 af[8], bfr[4], aw;
#pragma unroll
      for (int im = 0; im < 8; ++im) {
        int row = 16 + im * 16 + fr;                    // row&7 == fr&7
        af[im] = *(const short8*)(base + row * 128 + (((s * 4 + fq) ^ (fr & 7)) * 16));
      }
#pragma unroll
      for (int in = 0; in < 4; ++in) {
        int row = wn + in * 16 + fr;
        bfr[in] = *(const short8*)(base + AREG + row * 128 + (((s * 4 + fq) ^ (fr & 7)) * 16));
      }
      aw = *(const short8*)(base + fr * 128 + (((s * 4 + fq) ^ (fr & 7)) * 16));
#pragma unroll
      for (int im = 0; im < 8; ++im)
#pragma unroll
        for (int in = 0; in < 4; ++in)
          acc[im][in] = __builtin_amdgcn_mfma_f32_16x16x32_bf16(
              af[im], bfr[in], acc[im][in], 0, 0, 0);
#pragma unroll
      for (int in = 0; in < 4; ++in)    // warmup rows t in [m0-16, m0)
        accw[in] = __builtin_amdgcn_mfma_f32_16x16x32_bf16(
            aw, bfr[in], accw[in], 0, 0, 0);
    }

    asm volatile("s_barrier" ::: "memory");   // buf consumed; safe to refill
  }

  // ---- epilogue: S-tile (144 x 128, bf16, stride 132) into LDS ----
  uint16_t* Sl = (uint16_t*)lds;
#pragma unroll
  for (int im = 0; im < 8; ++im)
#pragma unroll
    for (int in = 0; in < 4; ++in)
#pragma unroll
      for (int r = 0; r < 4; ++r)
        Sl[(16 + im * 16 + fq * 4 + r) * SSTR + wn + in * 16 + fr] =
            f2bf(acc[im][in][r]);
#pragma unroll
  for (int in = 0; in < 4; ++in)
#pragma unroll
    for (int r = 0; r < 4; ++r)
      Sl[(fq * 4 + r) * SSTR + wn + in * 16 + fr] = f2bf(accw[in][r]);
  __syncthreads();

  // ---- scan: 1 thread per column, 128 t-steps, 16-step warmup ----
  const int col = tid;                  // 0..127
  const float av = a[n0 + col];
  float h = 0.f;
  if (m0 != 0) {
#pragma unroll
    for (int i = 0; i < 16; ++i)
      h = av * h + bf2f(Sl[i * SSTR + col]);
  }
  float* op = out + (size_t)m0 * HDIM + n0 + col;
#pragma unroll 8
  for (int i = 0; i < 128; ++i) {
    h = av * h + bf2f(Sl[(16 + i) * SSTR + col]);
    op[(size_t)i * HDIM] = h;
  }
}

extern "C" void kernel_launch(void* const* d_in, const int* in_sizes, int n_in,
                              void* d_out, int out_size, void* d_ws, size_t ws_size,
                              hipStream_t stream) {
  const float* x = (const float*)d_in[0];   // (T, H)
  const float* a = (const float*)d_in[1];   // (H,)
  const float* B = (const float*)d_in[2];   // (H, H)
  float* out = (float*)d_out;               // (1, T, H) fp32

  uint16_t* xb  = (uint16_t*)d_ws;                                        // 16 MB
  uint16_t* Btb = (uint16_t*)((char*)d_ws + (size_t)16 * 1024 * 1024);    //  8 MB

  // x -> bf16  and  B -> Bt bf16 (fused)
  prep<<<4096 + 1024, 256, 0, stream>>>(x, B, xb, Btb);
  // fused GEMM + recurrence: 512 blocks x 128 threads (2 waves, 128x64 each)
  gemm_scan<<<dim3(HDIM / BN, TDIM / BM), 128, 0, stream>>>(xb, Btb, a, out);
}

// Round 2
// 137.256 us; speedup vs baseline: 1.0683x; 1.0683x over previous
//
#include <hip/hip_runtime.h>
#include <stdint.h>

// Problem dims
#define TDIM 4096
#define HDIM 2048   // N and K of the GEMM

// GEMM tile
#define BM 256
#define BN 128
#define BK 64
#define NKT (HDIM / BK)   // 32
// LDS: per buffer = A region (272 rows = 34 groups of 8 rows, 1KB/group)
//      + B region (128 rows = 16 groups), 128B per row (BK=64 bf16)
#define AREG  34816
#define PERBUF 51200
#define SSTR   132        // S-tile row stride in elements (breaks bank conflicts)

typedef short short8 __attribute__((ext_vector_type(8)));
typedef float f32x4 __attribute__((ext_vector_type(4)));

__device__ __forceinline__ uint16_t f2bf(float f) {
  uint32_t u = __builtin_bit_cast(uint32_t, f);
  u += 0x7fffu + ((u >> 16) & 1u);          // round-to-nearest-even
  return (uint16_t)(u >> 16);
}
__device__ __forceinline__ float bf2f(uint32_t h) {   // low 16 bits used
  uint32_t u = h << 16;
  return __builtin_bit_cast(float, u);
}

__device__ __forceinline__ void async_copy16(const void* gsrc, void* ldst) {
  __builtin_amdgcn_global_load_lds(
      (const __attribute__((address_space(1))) uint32_t*)gsrc,
      (__attribute__((address_space(3))) uint32_t*)ldst,
      16, 0, 0);
}

// ------------- prep: cvt x (fp32->bf16) + transpose/cvt B -> Bt -------------
__global__ void prep(const float* __restrict__ x, const float* __restrict__ B,
                     uint16_t* __restrict__ xb, uint16_t* __restrict__ Bt) {
  __shared__ uint16_t tile[64][68];
  const int t = threadIdx.x;
  if (blockIdx.x < 4096) {
    size_t i = ((size_t)blockIdx.x * 256 + t) * 8;
    float4 v0 = *(const float4*)(x + i);
    float4 v1 = *(const float4*)(x + i + 4);
    union { uint16_t h[8]; uint4 v; } o;
    o.h[0] = f2bf(v0.x); o.h[1] = f2bf(v0.y); o.h[2] = f2bf(v0.z); o.h[3] = f2bf(v0.w);
    o.h[4] = f2bf(v1.x); o.h[5] = f2bf(v1.y); o.h[6] = f2bf(v1.z); o.h[7] = f2bf(v1.w);
    *(uint4*)(xb + i) = o.v;
  } else {
    const int bid = blockIdx.x - 4096;
    const int n0 = (bid & 31) * 64;
    const int k0 = (bid >> 5) * 64;
    {
      const int r  = t >> 4;
      const int c4 = (t & 15) * 4;
#pragma unroll
      for (int i = 0; i < 4; ++i) {
        int rr = r + i * 16;
        float4 v = *(const float4*)&B[(size_t)(k0 + rr) * HDIM + n0 + c4];
        union { uint16_t h[4]; uint2 u; } o;
        o.h[0] = f2bf(v.x); o.h[1] = f2bf(v.y); o.h[2] = f2bf(v.z); o.h[3] = f2bf(v.w);
        *(uint2*)&tile[rr][c4] = o.u;
      }
    }
    __syncthreads();
    {
      const int nr = t >> 2;
      const int kc = (t & 3) * 4;
#pragma unroll
      for (int i = 0; i < 4; ++i) {
        int kk = kc + i * 16;
        union { uint16_t h[4]; uint2 u; } o;
        o.h[0] = tile[kk][nr];     o.h[1] = tile[kk + 1][nr];
        o.h[2] = tile[kk + 2][nr]; o.h[3] = tile[kk + 3][nr];
        *(uint2*)&Bt[(size_t)(n0 + nr) * HDIM + k0 + kk] = o.u;
      }
    }
  }
}

// --------- fused GEMM + causal exp-decay recurrence (scan) ---------
// S[t][n] = sum_k A[t][k]*Bt[n][k]; out[t][h] = S[t][h] + a[h]*out[t-1][h].
// 512 threads = 8 waves (4M x 2N), each a 64x64 tile (4x4 acc): the wave
// tile forced by occupancy (8 waves/CU x 256 CU -> 4096 cells/wave).
// BM=256 stages the B-panel once per 256 M-rows: per-CU/kt staging writes
// 68->50 KB vs 2x(128x128) blocks; grid 256 = 1 block/CU, 2 waves/SIMD
// (same latency hiding as the 48.4us round-0 config).
// BK=64: 128B rows + XOR-8 chunk swizzle = conflict-free.
// 16 warmup rows on waves 0,1; in-LDS S-tile scan epilogue (|a| <= 2^-5).
__global__ __launch_bounds__(512, 2) void gemm_scan(
    const uint16_t* __restrict__ A, const uint16_t* __restrict__ Bt,
    const float* __restrict__ a, float* __restrict__ out) {
  __shared__ __align__(16) char lds[2 * PERBUF];   // 102400 >= 272*132*2=71808

  const int tid  = threadIdx.x;
  const int lane = tid & 63;
  const int wave = tid >> 6;            // 0..7
  const int wm = (wave >> 1) * 64;      // wave row offset {0,64,128,192}
  const int wn = (wave & 1) * 64;       // wave col offset {0,64}

  // XCD-chunked bijective swizzle: 256 blocks, 8 XCDs, 32 consecutive
  // logical tiles per XCD -> the 16 blocks sharing an A-panel colocate.
  const int flat = blockIdx.y * gridDim.x + blockIdx.x;
  const int logi = (flat & 7) * 32 + (flat >> 3);
  const int m0 = (logi >> 4) * BM;      // 16 m-blocks
  const int n0 = (logi & 15) * BN;      // 16 n-blocks

  f32x4 acc[4][4] = {};
  f32x4 accw[4] = {};                   // warmup rows (waves 0,1 only)

  // staging: one instr = 8 rows x 128B (1KB); lane l: row lr=l>>3, slot l&7,
  // fetches global chunk (l&7)^lr -> LDS slot c of row r holds chunk c^(r&7)
  const int lr = lane >> 3;             // 0..7
  const int gc = (lane & 7) ^ lr;       // swizzled 16B chunk to fetch

  const int fr = lane & 15;
  const int fq = lane >> 4;             // 0..3

  // A: 34 groups of 8 rows (t in [m0-16, m0+256)); wave w takes g=4w..4w+3,
  // waves 0,1 additionally take g=32,33.  B: 16 groups; wave w takes 2w,2w+1.
  auto issue_tile = [&](int kt2) {
    size_t koff = (size_t)kt2 * (BK * 2);
    char* dst = lds + (kt2 & 1) * PERBUF;
#pragma unroll
    for (int i = 0; i < 4; ++i) {
      int g = wave * 4 + i;
      int row = m0 - 16 + g * 8 + lr;
      if (row < 0) row = 0;             // m0==0: garbage rows, never used
      async_copy16((const char*)A + ((size_t)row * HDIM + gc * 8) * 2 + koff,
                   dst + g * 1024);
    }
    if (wave < 2) {
      int g = 32 + wave;
      int row = m0 - 16 + g * 8 + lr;   // rows m0+240..m0+255: always valid
      async_copy16((const char*)A + ((size_t)row * HDIM + gc * 8) * 2 + koff,
                   dst + g * 1024);
    }
#pragma unroll
    for (int i = 0; i < 2; ++i) {
      int g = wave * 2 + i;
      int row = n0 + g * 8 + lr;
      async_copy16((const char*)Bt + ((size_t)row * HDIM + gc * 8) * 2 + koff,
                   dst + AREG + g * 1024);
    }
  };

  issue_tile(0);
  for (int kt = 0; kt < NKT; ++kt) {
    if (kt + 1 < NKT) {
      issue_tile(kt + 1);
      // wait only this tile's loads; next tile's (7 or 6) stay in flight
      if (wave < 2) asm volatile("s_waitcnt vmcnt(7)" ::: "memory");
      else          asm volatile("s_waitcnt vmcnt(6)" ::: "memory");
    } else {
      asm volatile("s_waitcnt vmcnt(0)" ::: "memory");
    }
    asm volatile("s_barrier" ::: "memory");

    const char* base = lds + (kt & 1) * PERBUF;
#pragma unroll
    for (int s = 0; s < 2; ++s) {       // two K=32 halves of the 128B row
      short8 af[4], bfr[4], aw;
#pragma unroll
      for (int im = 0; im < 4; ++im) {
        int row = 16 + wm + im * 16 + fr;               // row&7 == fr&7
        af[im] = *(const short8*)(base + row * 128 + (((s * 4 + fq) ^ (fr & 7)) * 16));
      }
#pragma unroll
      for (int in = 0; in < 4; ++in) {
        int row = wn + in * 16 + fr;
        bfr[in] = *(const short8*)(base + AREG + row * 128 + (((s * 4 + fq) ^ (fr & 7)) * 16));
      }
#pragma unroll
      for (int im = 0; im < 4; ++im)
#pragma unroll
        for (int in = 0; in < 4; ++in)
          acc[im][in] = __builtin_amdgcn_mfma_f32_16x16x32_bf16(
              af[im], bfr[in], acc[im][in], 0, 0, 0);
      if (wave < 2) {                   // warmup rows t in [m0-16, m0)
        aw = *(const short8*)(base + fr * 128 + (((s * 4 + fq) ^ (fr & 7)) * 16));
#pragma unroll
        for (int in = 0; in < 4; ++in)
          accw[in] = __builtin_amdgcn_mfma_f32_16x16x32_bf16(
              aw, bfr[in], accw[in], 0, 0, 0);
      }
    }

    asm volatile("s_barrier" ::: "memory");   // buf consumed; safe to refill
  }

  // ---- epilogue: S-tile (272 x 128, bf16, stride 132) into LDS ----
  uint16_t* Sl = (uint16_t*)lds;
#pragma unroll
  for (int im = 0; im < 4; ++im)
#pragma unroll
    for (int in = 0; in < 4; ++in)
#pragma unroll
      for (int r = 0; r < 4; ++r)
        Sl[(16 + wm + im * 16 + fq * 4 + r) * SSTR + wn + in * 16 + fr] =
            f2bf(acc[im][in][r]);
  if (wave < 2) {
#pragma unroll
    for (int in = 0; in < 4; ++in)
#pragma unroll
      for (int r = 0; r < 4; ++r)
        Sl[(fq * 4 + r) * SSTR + wn + in * 16 + fr] = f2bf(accw[in][r]);
  }
  __syncthreads();

  // ---- scan: 4 threads per column, 64 t-steps each, 16-step warmup ----
  const int col   = tid & 127;
  const int chunk = tid >> 7;           // 0..3
  const float av  = a[n0 + col];
  float h = 0.f;
  if (!(m0 == 0 && chunk == 0)) {
#pragma unroll
    for (int i = 0; i < 16; ++i)
      h = av * h + bf2f(Sl[(chunk * 64 + i) * SSTR + col]);
  }
  float* op = out + (size_t)(m0 + chunk * 64) * HDIM + n0 + col;
#pragma unroll
  for (int i = 0; i < 64; ++i) {
    h = av * h + bf2f(Sl[(chunk * 64 + 16 + i) * SSTR + col]);
    op[(size_t)i * HDIM] = h;
  }
}

extern "C" void kernel_launch(void* const* d_in, const int* in_sizes, int n_in,
                              void* d_out, int out_size, void* d_ws, size_t ws_size,
                              hipStream_t stream) {
  const float* x = (const float*)d_in[0];   // (T, H)
  const float* a = (const float*)d_in[1];   // (H,)
  const float* B = (const float*)d_in[2];   // (H, H)
  float* out = (float*)d_out;               // (1, T, H) fp32

  uint16_t* xb  = (uint16_t*)d_ws;                                        // 16 MB
  uint16_t* Btb = (uint16_t*)((char*)d_ws + (size_t)16 * 1024 * 1024);    //  8 MB

  // x -> bf16  and  B -> Bt bf16 (fused)
  prep<<<4096 + 1024, 256, 0, stream>>>(x, B, xb, Btb);
  // fused GEMM + recurrence: 256 blocks x 512 threads (8 waves, 64x64 each)
  gemm_scan<<<dim3(HDIM / BN, TDIM / BM), 512, 0, stream>>>(xb, Btb, a, out);
}

// Round 3
// 137.077 us; speedup vs baseline: 1.0697x; 1.0013x over previous
//
#include <hip/hip_runtime.h>
#include <stdint.h>

// Problem dims
#define TDIM 4096
#define HDIM 2048   // N and K of the GEMM

// GEMM tile
#define BM 256
#define BN 128
#define BK 64
#define NKT (HDIM / BK)   // 32
// LDS: per buffer = A region (272 rows = 34 groups of 8 rows, 1KB/group)
//      + B region (128 rows = 16 groups), 128B per row (BK=64 bf16)
#define AREG  34816
#define PERBUF 51200
#define SSTR   132        // S-tile row stride in elements (breaks bank conflicts)

typedef short short8 __attribute__((ext_vector_type(8)));
typedef float f32x4 __attribute__((ext_vector_type(4)));

__device__ __forceinline__ uint16_t f2bf(float f) {
  uint32_t u = __builtin_bit_cast(uint32_t, f);
  u += 0x7fffu + ((u >> 16) & 1u);          // round-to-nearest-even
  return (uint16_t)(u >> 16);
}
__device__ __forceinline__ float bf2f(uint32_t h) {   // low 16 bits used
  uint32_t u = h << 16;
  return __builtin_bit_cast(float, u);
}

__device__ __forceinline__ void async_copy16(const void* gsrc, void* ldst) {
  __builtin_amdgcn_global_load_lds(
      (const __attribute__((address_space(1))) uint32_t*)gsrc,
      (__attribute__((address_space(3))) uint32_t*)ldst,
      16, 0, 0);
}

// ------------- prep: cvt x (fp32->bf16) + transpose/cvt B -> Bt -------------
__global__ void prep(const float* __restrict__ x, const float* __restrict__ B,
                     uint16_t* __restrict__ xb, uint16_t* __restrict__ Bt) {
  __shared__ uint16_t tile[64][70];   // stride 70: even (uint2-aligned), ~2-way banks
  const int t = threadIdx.x;
  if (blockIdx.x < 4096) {
    size_t i = ((size_t)blockIdx.x * 256 + t) * 8;
    float4 v0 = *(const float4*)(x + i);
    float4 v1 = *(const float4*)(x + i + 4);
    union { uint16_t h[8]; uint4 v; } o;
    o.h[0] = f2bf(v0.x); o.h[1] = f2bf(v0.y); o.h[2] = f2bf(v0.z); o.h[3] = f2bf(v0.w);
    o.h[4] = f2bf(v1.x); o.h[5] = f2bf(v1.y); o.h[6] = f2bf(v1.z); o.h[7] = f2bf(v1.w);
    *(uint4*)(xb + i) = o.v;
  } else {
    const int bid = blockIdx.x - 4096;
    const int n0 = (bid & 31) * 64;
    const int k0 = (bid >> 5) * 64;
    {
      const int r  = t >> 4;
      const int c4 = (t & 15) * 4;
#pragma unroll
      for (int i = 0; i < 4; ++i) {
        int rr = r + i * 16;
        float4 v = *(const float4*)&B[(size_t)(k0 + rr) * HDIM + n0 + c4];
        union { uint16_t h[4]; uint2 u; } o;
        o.h[0] = f2bf(v.x); o.h[1] = f2bf(v.y); o.h[2] = f2bf(v.z); o.h[3] = f2bf(v.w);
        *(uint2*)&tile[rr][c4] = o.u;
      }
    }
    __syncthreads();
    {
      // 16B stores: 8 threads per Bt row, 128B contiguous per row
      const int nr8 = t >> 3;           // 0..31
      const int kc8 = (t & 7) * 8;      // 0..56
#pragma unroll
      for (int i = 0; i < 2; ++i) {
        int nr = nr8 + i * 32;
        union { uint16_t h[8]; uint4 v; } o;
#pragma unroll
        for (int j = 0; j < 8; ++j) o.h[j] = tile[kc8 + j][nr];
        *(uint4*)&Bt[(size_t)(n0 + nr) * HDIM + k0 + kc8] = o.v;
      }
    }
  }
}

// --------- fused GEMM + causal exp-decay recurrence (scan) ---------
// S[t][n] = sum_k A[t][k]*Bt[n][k]; out[t][h] = S[t][h] + a[h]*out[t-1][h].
// 512 threads = 8 waves (4M x 2N), 64x64 per wave (occupancy-forced shape).
// BM=256: B-panel staged once per 256 M-rows; grid 256 = 1 block/CU,
// 2 waves/SIMD.  Phase-split schedule (T3/T4/T5): per K-tile two phases,
// each {stage-issue | counted vmcnt | barrier | ds_read | lgkmcnt(0)+
// sched_barrier | setprio(1) MFMA cluster setprio(0)}.  Phase-1 ds_reads
// hoist before its barrier (latency hides under barrier wait); vmcnt(4)
// once per kt keeps next tile's loads in flight (never drains in-loop).
// Read/write buffer ordering identical to the proven 2-barrier kernel.
// BK=64: 128B rows + XOR-8 chunk swizzle = conflict-free.
// 16 warmup rows on waves 0,1; in-LDS S-tile scan epilogue (|a| <= 2^-5).
__global__ __launch_bounds__(512, 2) void gemm_scan(
    const uint16_t* __restrict__ A, const uint16_t* __restrict__ Bt,
    const float* __restrict__ a, float* __restrict__ out) {
  __shared__ __align__(16) char lds[2 * PERBUF];   // 102400

  const int tid  = threadIdx.x;
  const int lane = tid & 63;
  const int wave = tid >> 6;            // 0..7
  const int wm = (wave >> 1) * 64;      // wave row offset {0,64,128,192}
  const int wn = (wave & 1) * 64;       // wave col offset {0,64}

  // XCD-chunked bijective swizzle: 256 blocks, 8 XCDs, 32 consecutive
  // logical tiles per XCD -> the 16 blocks sharing an A-panel colocate.
  const int flat = blockIdx.y * gridDim.x + blockIdx.x;
  const int logi = (flat & 7) * 32 + (flat >> 3);
  const int m0 = (logi >> 4) * BM;      // 16 m-blocks
  const int n0 = (logi & 15) * BN;      // 16 n-blocks

  f32x4 acc[4][4] = {};
  f32x4 accw[4] = {};                   // warmup rows (waves 0,1 only)

  // staging: one instr = 8 rows x 128B (1KB); lane l: row lr=l>>3, slot l&7,
  // fetches global chunk (l&7)^lr -> LDS slot c of row r holds chunk c^(r&7)
  const int lr = lane >> 3;             // 0..7
  const int gc = (lane & 7) ^ lr;       // swizzled 16B chunk to fetch

  const int fr = lane & 15;
  const int fq = lane >> 4;             // 0..3

  // A: 34 groups of 8 rows (t in [m0-16, m0+256)); wave w takes g=4w..4w+3
  // (phase 0); B: 16 groups, wave w takes 2w,2w+1; waves 0,1 also take
  // A groups 32,33 (phase 1).  Uniform 4 loads in phase 0 -> vmcnt(4).
  auto issue_A = [&](int kt2) {
    size_t koff = (size_t)kt2 * (BK * 2);
    char* dst = lds + (kt2 & 1) * PERBUF;
#pragma unroll
    for (int i = 0; i < 4; ++i) {
      int g = wave * 4 + i;
      int row = m0 - 16 + g * 8 + lr;
      if (row < 0) row = 0;             // m0==0: garbage rows, never used
      async_copy16((const char*)A + ((size_t)row * HDIM + gc * 8) * 2 + koff,
                   dst + g * 1024);
    }
  };
  auto issue_B = [&](int kt2) {
    size_t koff = (size_t)kt2 * (BK * 2);
    char* dst = lds + (kt2 & 1) * PERBUF;
#pragma unroll
    for (int i = 0; i < 2; ++i) {
      int g = wave * 2 + i;
      int row = n0 + g * 8 + lr;
      async_copy16((const char*)Bt + ((size_t)row * HDIM + gc * 8) * 2 + koff,
                   dst + AREG + g * 1024);
    }
    if (wave < 2) {
      int g = 32 + wave;
      int row = m0 - 16 + g * 8 + lr;   // rows m0+240..m0+255: always valid
      async_copy16((const char*)A + ((size_t)row * HDIM + gc * 8) * 2 + koff,
                   dst + g * 1024);
    }
  };

  issue_A(0);
  issue_B(0);

  for (int kt = 0; kt < NKT; ++kt) {
    const char* base = lds + (kt & 1) * PERBUF;

    // ---------- phase 0: K-half s=0 ----------
    if (kt + 1 < NKT) {
      issue_A(kt + 1);
      // wait this tile's 6-7 loads; the 4 just-issued stay in flight
      asm volatile("s_waitcnt vmcnt(4)" ::: "memory");
    } else {
      asm volatile("s_waitcnt vmcnt(0)" ::: "memory");
    }
    asm volatile("s_barrier" ::: "memory");
    {
      short8 af[4], bfr[4];
#pragma unroll
      for (int im = 0; im < 4; ++im)
        af[im] = *(const short8*)(base + (16 + wm + im * 16 + fr) * 128 +
                                  ((fq ^ (fr & 7)) * 16));
#pragma unroll
      for (int in = 0; in < 4; ++in)
        bfr[in] = *(const short8*)(base + AREG + (wn + in * 16 + fr) * 128 +
                                   ((fq ^ (fr & 7)) * 16));
      short8 aw = af[0];
      if (wave < 2)
        aw = *(const short8*)(base + fr * 128 + ((fq ^ (fr & 7)) * 16));
      asm volatile("s_waitcnt lgkmcnt(0)" ::: "memory");
      __builtin_amdgcn_sched_barrier(0);
      __builtin_amdgcn_s_setprio(1);
#pragma unroll
      for (int im = 0; im < 4; ++im)
#pragma unroll
        for (int in = 0; in < 4; ++in)
          acc[im][in] = __builtin_amdgcn_mfma_f32_16x16x32_bf16(
              af[im], bfr[in], acc[im][in], 0, 0, 0);
      if (wave < 2) {
#pragma unroll
        for (int in = 0; in < 4; ++in)
          accw[in] = __builtin_amdgcn_mfma_f32_16x16x32_bf16(
              aw, bfr[in], accw[in], 0, 0, 0);
      }
      __builtin_amdgcn_s_setprio(0);
    }

    // ---------- phase 1: K-half s=1 ----------
    {
      short8 af[4], bfr[4];
#pragma unroll
      for (int im = 0; im < 4; ++im)
        af[im] = *(const short8*)(base + (16 + wm + im * 16 + fr) * 128 +
                                  (((4 + fq) ^ (fr & 7)) * 16));
#pragma unroll
      for (int in = 0; in < 4; ++in)
        bfr[in] = *(const short8*)(base + AREG + (wn + in * 16 + fr) * 128 +
                                   (((4 + fq) ^ (fr & 7)) * 16));
      short8 aw = af[0];
      if (wave < 2)
        aw = *(const short8*)(base + fr * 128 + (((4 + fq) ^ (fr & 7)) * 16));
      if (kt + 1 < NKT) issue_B(kt + 1);
      // barrier AFTER the reads: next iter re-stages this buffer only once
      // every wave's reads are enqueued; read latency hides under barrier.
      asm volatile("s_barrier" ::: "memory");
      asm volatile("s_waitcnt lgkmcnt(0)" ::: "memory");
      __builtin_amdgcn_sched_barrier(0);
      __builtin_amdgcn_s_setprio(1);
#pragma unroll
      for (int im = 0; im < 4; ++im)
#pragma unroll
        for (int in = 0; in < 4; ++in)
          acc[im][in] = __builtin_amdgcn_mfma_f32_16x16x32_bf16(
              af[im], bfr[in], acc[im][in], 0, 0, 0);
      if (wave < 2) {
#pragma unroll
        for (int in = 0; in < 4; ++in)
          accw[in] = __builtin_amdgcn_mfma_f32_16x16x32_bf16(
              aw, bfr[in], accw[in], 0, 0, 0);
      }
      __builtin_amdgcn_s_setprio(0);
    }
  }

  __syncthreads();   // all reads of both buffers done before S-tile overwrite

  // ---- epilogue: S-tile (272 x 128, bf16, stride 132) into LDS ----
  uint16_t* Sl = (uint16_t*)lds;
#pragma unroll
  for (int im = 0; im < 4; ++im)
#pragma unroll
    for (int in = 0; in < 4; ++in)
#pragma unroll
      for (int r = 0; r < 4; ++r)
        Sl[(16 + wm + im * 16 + fq * 4 + r) * SSTR + wn + in * 16 + fr] =
            f2bf(acc[im][in][r]);
  if (wave < 2) {
#pragma unroll
    for (int in = 0; in < 4; ++in)
#pragma unroll
      for (int r = 0; r < 4; ++r)
        Sl[(fq * 4 + r) * SSTR + wn + in * 16 + fr] = f2bf(accw[in][r]);
  }
  __syncthreads();

  // ---- scan: 4 threads per column, 64 t-steps each, 16-step warmup ----
  const int col   = tid & 127;
  const int chunk = tid >> 7;           // 0..3
  const float av  = a[n0 + col];
  float h = 0.f;
  if (!(m0 == 0 && chunk == 0)) {
#pragma unroll
    for (int i = 0; i < 16; ++i)
      h = av * h + bf2f(Sl[(chunk * 64 + i) * SSTR + col]);
  }
  float* op = out + (size_t)(m0 + chunk * 64) * HDIM + n0 + col;
#pragma unroll
  for (int i = 0; i < 64; ++i) {
    h = av * h + bf2f(Sl[(chunk * 64 + 16 + i) * SSTR + col]);
    op[(size_t)i * HDIM] = h;
  }
}

extern "C" void kernel_launch(void* const* d_in, const int* in_sizes, int n_in,
                              void* d_out, int out_size, void* d_ws, size_t ws_size,
                              hipStream_t stream) {
  const float* x = (const float*)d_in[0];   // (T, H)
  const float* a = (const float*)d_in[1];   // (H,)
  const float* B = (const float*)d_in[2];   // (H, H)
  float* out = (float*)d_out;               // (1, T, H) fp32

  uint16_t* xb  = (uint16_t*)d_ws;                                        // 16 MB
  uint16_t* Btb = (uint16_t*)((char*)d_ws + (size_t)16 * 1024 * 1024);    //  8 MB

  // x -> bf16  and  B -> Bt bf16 (fused)
  prep<<<4096 + 1024, 256, 0, stream>>>(x, B, xb, Btb);
  // fused GEMM + recurrence: 256 blocks x 512 threads (8 waves, 64x64 each)
  gemm_scan<<<dim3(HDIM / BN, TDIM / BM), 512, 0, stream>>>(xb, Btb, a, out);
}